// Round 12
// baseline (37.167 us; speedup 1.0000x reference)
//
#include <hip/hip_runtime.h>
#include <math.h>

// GumbelSampler: iterative gumbel-softmax k-hot (k=64) over 256 rows of 16384,
// then straight-through hard top-64.
//
// Round-12: E-PAIR BLOCKS, single dispatch. One block per (t,b) handles BOTH
// ensemble rows (e=0,1):
//  - output zero-fill is fully DENSE float4 (the stride-2 4B store pattern and
//    its cross-block L2 merging are gone), issued first with no dependencies;
//  - scores read once per pair (float4 gives both e) -> scores traffic halved;
//  - two histograms in one pass; wave0/wave1 run the two cutoffs and the two
//    64-iteration dynamics CONCURRENTLY on different SIMDs;
//  - 512-thread parallel exact rank (lax.top_k tie semantics) writes the ones.
// Selection math per row (full-row NCAND=256 bit-histogram cut, prefix-ordered
// compaction, ex-space dynamics with 90-bit-headroom po2 rebase, exact rank)
// is value-identical to rounds 9-11 (absmax 0.0 throughout).

#define M_ELEMS 16384
#define EPT     16                  // m-elements per thread per e
#define KSEL    64
#define NCAND   256
#define CPL     4
#define NBINS   4096                // transformed f0 bits >> 20
#define THRESH  (M_ELEMS - NCAND)   // 16128: cut where CntLT >= THRESH
#define C10     14.42695019f        // log2(e)/tau

// ---- DPP wave64 helpers ----
template <int CTRL, int RM = 0xF>
__device__ __forceinline__ float dpp_f(float x, float identity) {
    return __int_as_float(__builtin_amdgcn_update_dpp(
        __float_as_int(identity), __float_as_int(x), CTRL, RM, 0xF, false));
}
template <int CTRL, int RM = 0xF>
__device__ __forceinline__ unsigned dpp_u(unsigned x, unsigned identity) {
    return (unsigned)__builtin_amdgcn_update_dpp(
        (int)identity, (int)x, CTRL, RM, 0xF, false);
}
__device__ __forceinline__ float wave_sum_bcast(float x) {
    x += dpp_f<0x111>(x, 0.0f);
    x += dpp_f<0x112>(x, 0.0f);
    x += dpp_f<0x114>(x, 0.0f);
    x += dpp_f<0x118>(x, 0.0f);
    x += dpp_f<0x142>(x, 0.0f);
    x += dpp_f<0x143>(x, 0.0f);
    return __int_as_float(__builtin_amdgcn_readlane(__float_as_int(x), 63));
}
__device__ __forceinline__ float wave_fmax_bcast(float x) {
    x = fmaxf(x, dpp_f<0x111>(x, -INFINITY));
    x = fmaxf(x, dpp_f<0x112>(x, -INFINITY));
    x = fmaxf(x, dpp_f<0x114>(x, -INFINITY));
    x = fmaxf(x, dpp_f<0x118>(x, -INFINITY));
    x = fmaxf(x, dpp_f<0x142>(x, -INFINITY));
    x = fmaxf(x, dpp_f<0x143>(x, -INFINITY));
    return __int_as_float(__builtin_amdgcn_readlane(__float_as_int(x), 63));
}
__device__ __forceinline__ unsigned wave_prefix_incl(unsigned x) {
    x += dpp_u<0x111>(x, 0u);
    x += dpp_u<0x112>(x, 0u);
    x += dpp_u<0x114>(x, 0u);
    x += dpp_u<0x118>(x, 0u);
    x += dpp_u<0x142, 0xA>(x, 0u);     // row_bcast:15 -> rows 1,3
    x += dpp_u<0x143, 0xC>(x, 0u);     // row_bcast:31 -> rows 2,3
    return x;
}

__global__ __launch_bounds__(1024, 4) void gumbel_pair_kernel(
    const float* __restrict__ scores,
    const float* __restrict__ gumbel,
    float* __restrict__ out)
{
    const int tid  = threadIdx.x;
    const int lane = tid & 63;
    const int wid  = tid >> 6;
    const int pair = blockIdx.x;        // 0..127 = (t,b)
    const int t_ = pair >> 6;
    const int b  = pair & 63;
    const int r0 = t_ * 128 + 2 * b;    // e=0 row; e=1 row is r0+1

    __shared__ unsigned int           hist[2][NBINS];   // 32 KB
    __shared__ __align__(16) float    cfb[2][NCAND];    // f0 -> kh
    __shared__ __align__(16) unsigned cib[2][NCAND];
    __shared__ unsigned int           wofs[2][16];
    __shared__ unsigned int           cutb[2], ccnt[2];

    float* obase = out + (size_t)(t_ * 64 + b) * (M_ELEMS * 2);

    // ---- P0a: dense zero-fill of this pair's whole output region ----
    // 32768 floats = 8192 float4; no dependencies -> issue first.
    const float4 z4 = make_float4(0.f, 0.f, 0.f, 0.f);
    #pragma unroll
    for (int g = 0; g < 8; ++g)
        *reinterpret_cast<float4*>(&obase[(size_t)(tid + (g << 10)) << 2]) = z4;

    // ---- P0b: load; m = tid*4 + j + g*4096; scores float4 -> both e ----
    float fv0[EPT], fv1[EPT];
    {
        const float* g0  = gumbel + (size_t)r0 * M_ELEMS;
        const float* g1  = g0 + M_ELEMS;
        const float* scb = scores + (size_t)b * (M_ELEMS * 2);
        #pragma unroll
        for (int g = 0; g < 4; ++g) {
            const int mb = (tid << 2) + (g << 12);
            const float4 ga = *reinterpret_cast<const float4*>(&g0[mb]);
            const float4 gb = *reinterpret_cast<const float4*>(&g1[mb]);
            const float4 sa = *reinterpret_cast<const float4*>(&scb[(size_t)mb * 2]);
            const float4 sb = *reinterpret_cast<const float4*>(&scb[(size_t)mb * 2 + 4]);
            fv0[g * 4 + 0] = sa.x + ga.x;   fv1[g * 4 + 0] = sa.y + gb.x;
            fv0[g * 4 + 1] = sa.z + ga.y;   fv1[g * 4 + 1] = sa.w + gb.y;
            fv0[g * 4 + 2] = sb.x + ga.z;   fv1[g * 4 + 2] = sb.y + gb.z;
            fv0[g * 4 + 3] = sb.z + ga.w;   fv1[g * 4 + 3] = sb.w + gb.w;
        }
    }
    {
        unsigned* hf = &hist[0][0];
        #pragma unroll
        for (int k = 0; k < (2 * NBINS) / 1024; ++k) hf[tid + (k << 10)] = 0u;
    }
    __syncthreads();                                   // B1: hist zeroed

    // ---- P1a: dual histogram of monotone-transformed f0 bits ----
    #pragma unroll
    for (int k = 0; k < EPT; ++k) {
        const unsigned u0 = __float_as_uint(fv0[k]);
        const unsigned k0 = u0 ^ (unsigned)(((int)u0 >> 31) | 0x80000000);
        atomicAdd(&hist[0][k0 >> 20], 1u);
        const unsigned u1 = __float_as_uint(fv1[k]);
        const unsigned k1 = u1 ^ (unsigned)(((int)u1 >> 31) | 0x80000000);
        atomicAdd(&hist[1][k1 >> 20], 1u);
    }
    __syncthreads();                                   // B2: hists complete

    // ---- P1b: waves 0,1 find cutoffs concurrently ----
    if (wid < 2) {
        const unsigned* h = hist[wid];
        unsigned part = 0;
        #pragma unroll 8
        for (int j = 0; j < 64; ++j)                   // rotated: bank-spread
            part += h[(lane << 6) + ((j + lane) & 63)];
        const unsigned P = wave_prefix_incl(part);
        const unsigned long long mk = __ballot(P >= THRESH);
        const int L = __builtin_ctzll(mk);
        const unsigned base = (L > 0)
            ? (unsigned)__builtin_amdgcn_readlane((int)P, L - 1) : 0u;
        const unsigned h2 = h[(L << 6) + lane];
        const unsigned p2 = wave_prefix_incl(h2) + base;
        const unsigned long long mk2 = __ballot(p2 >= THRESH);
        const int j2 = __builtin_ctzll(mk2);
        if (lane == 0) {
            cutb[wid] = (unsigned)((L << 6) + j2 + 1);
            ccnt[wid] = M_ELEMS - (unsigned)__builtin_amdgcn_readlane((int)p2, j2);
        }
    }
    __syncthreads();                                   // B3: cuts ready
    const unsigned cut0 = cutb[0] << 20, nc0 = ccnt[0];
    const unsigned cut1 = cutb[1] << 20, nc1 = ccnt[1];

    // ---- P1c: prefix-ordered compaction for both rows ----
    unsigned c0 = 0, h0 = 0, c1 = 0, h1 = 0;
    #pragma unroll
    for (int k = 0; k < EPT; ++k) {
        const unsigned u0 = __float_as_uint(fv0[k]);
        const unsigned k0 = u0 ^ (unsigned)(((int)u0 >> 31) | 0x80000000);
        const bool s0 = k0 >= cut0;
        h0 |= (s0 ? 1u : 0u) << k;  c0 += s0 ? 1u : 0u;
        const unsigned u1 = __float_as_uint(fv1[k]);
        const unsigned k1 = u1 ^ (unsigned)(((int)u1 >> 31) | 0x80000000);
        const bool s1 = k1 >= cut1;
        h1 |= (s1 ? 1u : 0u) << k;  c1 += s1 ? 1u : 0u;
    }
    const unsigned inc0 = wave_prefix_incl(c0);
    const unsigned inc1 = wave_prefix_incl(c1);
    if (lane == 63) { wofs[0][wid] = inc0; wofs[1][wid] = inc1; }
    __syncthreads();                                   // B4: wofs ready
    unsigned wb0 = 0, wb1 = 0;
    #pragma unroll
    for (int i = 0; i < 16; ++i) {
        wb0 += (i < wid) ? wofs[0][i] : 0u;
        wb1 += (i < wid) ? wofs[1][i] : 0u;
    }
    unsigned s0 = wb0 + inc0 - c0;
    unsigned s1 = wb1 + inc1 - c1;
    #pragma unroll
    for (int k = 0; k < EPT; ++k) {
        const unsigned mi = (unsigned)((tid << 2) + (k & 3) + ((k >> 2) << 12));
        if ((h0 >> k) & 1u) { cfb[0][s0] = fv0[k]; cib[0][s0] = mi; ++s0; }
        if ((h1 >> k) & 1u) { cfb[1][s1] = fv1[k]; cib[1][s1] = mi; ++s1; }
    }
    if ((unsigned)tid >= nc0 && tid < NCAND) {         // pad [nc, 256)
        cfb[0][tid] = -INFINITY;  cib[0][tid] = 0x7fffffffu;
    }
    if ((unsigned)tid >= nc1 && tid < NCAND) {
        cfb[1][tid] = -INFINITY;  cib[1][tid] = 0x7fffffffu;
    }
    __syncthreads();                                   // B5: candidates ready

    // ---- P2: waves 0,1 run the two rows' dynamics concurrently ----
    if (wid < 2) {
        float cf[CPL], cex[CPL], ckh[CPL];
        #pragma unroll
        for (int k = 0; k < CPL; ++k) cf[k] = cfb[wid][lane + (k << 6)];
        float cmax = fmaxf(fmaxf(cf[0], cf[1]), fmaxf(cf[2], cf[3]));
        cmax = wave_fmax_bcast(cmax);                  // row max (always cand)
        const float nbw = fmaf(-cmax, C10, 100.0f);    // top ex = 2^100
        #pragma unroll
        for (int k = 0; k < CPL; ++k) {
            cex[k] = __builtin_amdgcn_exp2f(fmaf(cf[k], C10, nbw));
            ckh[k] = 0.0f;
        }
        for (int it = 0; it < KSEL; ++it) {
            float gsum = wave_sum_bcast((cex[0] + cex[1]) + (cex[2] + cex[3]));
            // exponent-range rebase: 90 bits of headroom -> ~1x per row
            const int eb = (int)((__float_as_uint(gsum) >> 23) & 0xFF);
            if (eb < 127 + 10) {                       // gsum < 2^10
                int sh = 354 - eb;                     // rescale gsum -> ~2^100
                if (sh > 254) sh = 254;
                const float s = __uint_as_float((unsigned)sh << 23);
                #pragma unroll
                for (int k = 0; k < CPL; ++k) cex[k] *= s;
                gsum = wave_sum_bcast((cex[0] + cex[1]) + (cex[2] + cex[3]));
                if (!(gsum > 0.0f)) gsum = INFINITY;
            }
            const float rsum = __builtin_amdgcn_rcpf(gsum);
            #pragma unroll
            for (int k = 0; k < CPL; ++k) {
                ckh[k] = fmaf(cex[k], rsum, ckh[k]);          // kh += oh
                const float t  = fmaf(-cex[k], rsum, 1.0f);   // 1 - oh
                const float t2 = t * t;
                const float t4 = t2 * t2;
                const float t8 = t4 * t4;
                cex[k] = cex[k] * t8 * t2;                    // ex *= t^10
            }
        }
        #pragma unroll
        for (int k = 0; k < CPL; ++k) cfb[wid][lane + (k << 6)] = ckh[k]; // kh
    }
    __syncthreads();                                   // B6: kh + zeros drained

    // ---- P3: 512-thread exact rank (lax.top_k ties); winners store 1.0f ----
    if (tid < 2 * NCAND) {
        const int      sel = tid >> 8;                 // row e
        const int      j0  = tid & 255;
        const float    myv = cfb[sel][j0];
        const unsigned myi = cib[sel][j0];
        unsigned rank = 0;
        #pragma unroll 8
        for (int j = 0; j < NCAND; j += 4) {
            const float4 v  = *reinterpret_cast<const float4*>(&cfb[sel][j]);
            const uint4  ii = *reinterpret_cast<const uint4*>(&cib[sel][j]);
            rank += (v.x > myv || (v.x == myv && ii.x < myi)) ? 1u : 0u;
            rank += (v.y > myv || (v.y == myv && ii.y < myi)) ? 1u : 0u;
            rank += (v.z > myv || (v.z == myv && ii.z < myi)) ? 1u : 0u;
            rank += (v.w > myv || (v.w == myv && ii.w < myi)) ? 1u : 0u;
        }
        if (rank < KSEL && myi < M_ELEMS)
            obase[((size_t)myi << 1) + sel] = 1.0f;
    }
}

extern "C" void kernel_launch(void* const* d_in, const int* in_sizes, int n_in,
                              void* d_out, int out_size, void* d_ws, size_t ws_size,
                              hipStream_t stream) {
    const float* scores = (const float*)d_in[0];
    const float* gumbel = (const float*)d_in[1];
    float* out = (float*)d_out;
    const int rows  = in_sizes[1] / M_ELEMS;   // 256
    const int pairs = rows / 2;                // 128
    gumbel_pair_kernel<<<pairs, 1024, 0, stream>>>(scores, gumbel, out);
}

// Round 14
// 37.108 us; speedup vs baseline: 1.0016x; 1.0016x over previous
//
#include <hip/hip_runtime.h>
#include <math.h>

// GumbelSampler: iterative gumbel-softmax k-hot (k=64) over 256 rows of 16384,
// then straight-through hard top-64.
//
// Round-14 = round-13 with the zero-fill OOB fixed: out has 4,194,304 floats;
// 512 blocks x 8,192 floats each (bid<<13, 4x float4/thread). R13 used
// bid<<14 (2x overrun -> core dump).
//
//  K1 (512 x 512, 2 blocks/CU): half-row screen (R11-validated) -> local
//     top-128 per half-row via f0-bit histogram; dense decoupled zero-fill
//     issued after the histogram so stores drain under the LDS-bound
//     cutoff/compaction. K1->K2 dispatch order: zeros before ones.
//  K2 (256 x 256, BARRIER-FREE): each of 4 waves redundantly runs the
//     identical 64-iter ex-space dynamics on the full 256-candidate union,
//     writes kh/idx to a PRIVATE LDS quadrant (same-wave RAW = lgkmcnt only,
//     no __syncthreads), ranks its own 64 candidates (exact rank, lax.top_k
//     tie semantics), winners store 1.0f.
// Selection math is value-identical to rounds 9-12 (absmax 0.0 throughout).

#define M_ELEMS 16384
#define HALF_N  8192
#define EPT     16
#define KSEL    64
#define NCL     128                 // local candidates per half-row
#define NCAND   256                 // union per row
#define CPL     4
#define NBINS   4096                // transformed f0 bits >> 20
#define THRESH_L (HALF_N - NCL)     // 8064
#define C10     14.42695019f        // log2(e)/tau

// ---- DPP wave64 helpers ----
template <int CTRL, int RM = 0xF>
__device__ __forceinline__ float dpp_f(float x, float identity) {
    return __int_as_float(__builtin_amdgcn_update_dpp(
        __float_as_int(identity), __float_as_int(x), CTRL, RM, 0xF, false));
}
template <int CTRL, int RM = 0xF>
__device__ __forceinline__ unsigned dpp_u(unsigned x, unsigned identity) {
    return (unsigned)__builtin_amdgcn_update_dpp(
        (int)identity, (int)x, CTRL, RM, 0xF, false);
}
__device__ __forceinline__ float wave_sum_bcast(float x) {
    x += dpp_f<0x111>(x, 0.0f);
    x += dpp_f<0x112>(x, 0.0f);
    x += dpp_f<0x114>(x, 0.0f);
    x += dpp_f<0x118>(x, 0.0f);
    x += dpp_f<0x142>(x, 0.0f);
    x += dpp_f<0x143>(x, 0.0f);
    return __int_as_float(__builtin_amdgcn_readlane(__float_as_int(x), 63));
}
__device__ __forceinline__ float wave_fmax_bcast(float x) {
    x = fmaxf(x, dpp_f<0x111>(x, -INFINITY));
    x = fmaxf(x, dpp_f<0x112>(x, -INFINITY));
    x = fmaxf(x, dpp_f<0x114>(x, -INFINITY));
    x = fmaxf(x, dpp_f<0x118>(x, -INFINITY));
    x = fmaxf(x, dpp_f<0x142>(x, -INFINITY));
    x = fmaxf(x, dpp_f<0x143>(x, -INFINITY));
    return __int_as_float(__builtin_amdgcn_readlane(__float_as_int(x), 63));
}
__device__ __forceinline__ unsigned wave_prefix_incl(unsigned x) {
    x += dpp_u<0x111>(x, 0u);
    x += dpp_u<0x112>(x, 0u);
    x += dpp_u<0x114>(x, 0u);
    x += dpp_u<0x118>(x, 0u);
    x += dpp_u<0x142, 0xA>(x, 0u);     // row_bcast:15 -> rows 1,3
    x += dpp_u<0x143, 0xC>(x, 0u);     // row_bcast:31 -> rows 2,3
    return x;
}

// ======================= K1: half-row screen (512 x 512) =======================
__global__ __launch_bounds__(512, 4) void screen_kernel(
    const float* __restrict__ scores,
    const float* __restrict__ gumbel,
    float* __restrict__ cand_f,
    unsigned* __restrict__ cand_i,
    float* __restrict__ out)
{
    const int tid  = threadIdx.x;
    const int lane = tid & 63;
    const int wid  = tid >> 6;          // 0..7
    const int bid  = blockIdx.x;        // 0..511
    const int p    = bid & 255;
    const int half = bid >> 8;
    const int r    = ((p & 127) << 1) | (p >> 7);   // e-pair XCD swizzle
    const int b    = (r & 127) >> 1;
    const int e    = r & 1;

    __shared__ unsigned int hist[NBINS];   // 16 KB -> 2 blocks/CU
    __shared__ unsigned int wofs[8];
    __shared__ unsigned int cutbin;
    __shared__ unsigned int candcnt;

    // ---- load 8192 elems; k=g*4+j -> m = half*8192 + tid*4 + j + g*2048 ----
    float fv[EPT];
    {
        const float* gum = gumbel + (size_t)r * M_ELEMS;
        const float* scb = scores + (size_t)b * (M_ELEMS * 2);
        #pragma unroll
        for (int g = 0; g < 4; ++g) {
            const int mb = (half << 13) + (tid << 2) + (g << 11);
            const float4 gv = *reinterpret_cast<const float4*>(&gum[mb]);
            const float4 sa = *reinterpret_cast<const float4*>(&scb[(size_t)mb * 2]);
            const float4 sb = *reinterpret_cast<const float4*>(&scb[(size_t)mb * 2 + 4]);
            float s0, s1, s2, s3;
            if (e == 0) { s0 = sa.x; s1 = sa.z; s2 = sb.x; s3 = sb.z; }
            else        { s0 = sa.y; s1 = sa.w; s2 = sb.y; s3 = sb.w; }
            fv[g * 4 + 0] = s0 + gv.x;
            fv[g * 4 + 1] = s1 + gv.y;
            fv[g * 4 + 2] = s2 + gv.z;
            fv[g * 4 + 3] = s3 + gv.w;
        }
    }
    #pragma unroll
    for (int k = 0; k < NBINS / 512; ++k) hist[tid + k * 512] = 0u;
    __syncthreads();                                   // B1

    // ---- histogram of monotone-transformed f0 bits ----
    #pragma unroll
    for (int k = 0; k < EPT; ++k) {
        const unsigned u  = __float_as_uint(fv[k]);
        const unsigned tk = u ^ (unsigned)(((int)u >> 31) | 0x80000000);
        atomicAdd(&hist[tk >> 20], 1u);
    }

    // ---- dense decoupled zero-fill: slice [bid*8192, +8192) floats ----
    // 512 blocks x 8192 = 4,194,304 floats = exactly the output. Stores
    // drain under the LDS-bound phases below.
    {
        float* zs = out + ((size_t)bid << 13);
        const float4 z4 = make_float4(0.f, 0.f, 0.f, 0.f);
        #pragma unroll
        for (int g = 0; g < 4; ++g)
            *reinterpret_cast<float4*>(&zs[(size_t)(tid + (g << 9)) << 2]) = z4;
    }
    __syncthreads();                                   // B2: hist complete

    // ---- wave0 cutoff: min bin B with CntLT(B) >= 8064 ----
    if (wid == 0) {
        unsigned part = 0;
        #pragma unroll 8
        for (int j = 0; j < 64; ++j)                   // rotated: bank-spread
            part += hist[(lane << 6) + ((j + lane) & 63)];
        const unsigned P = wave_prefix_incl(part);
        const unsigned long long mk = __ballot(P >= THRESH_L);
        const int L = __builtin_ctzll(mk);
        const unsigned base = (L > 0)
            ? (unsigned)__builtin_amdgcn_readlane((int)P, L - 1) : 0u;
        const unsigned h2 = hist[(L << 6) + lane];
        const unsigned p2 = wave_prefix_incl(h2) + base;
        const unsigned long long mk2 = __ballot(p2 >= THRESH_L);
        const int j2 = __builtin_ctzll(mk2);
        if (lane == 0) {
            cutbin  = (unsigned)((L << 6) + j2 + 1);
            candcnt = HALF_N - (unsigned)__builtin_amdgcn_readlane((int)p2, j2);
        }
    }
    __syncthreads();                                   // B3
    const unsigned cutKey = cutbin << 20;
    const unsigned nc     = candcnt;                   // <= 128

    // ---- prefix-ordered compaction to d_ws[r*256 + half*128 ...] ----
    unsigned mycnt = 0, hitm = 0;
    #pragma unroll
    for (int k = 0; k < EPT; ++k) {
        const unsigned u  = __float_as_uint(fv[k]);
        const unsigned tk = u ^ (unsigned)(((int)u >> 31) | 0x80000000);
        const bool c = tk >= cutKey;
        hitm |= (c ? 1u : 0u) << k;
        mycnt += c ? 1u : 0u;
    }
    const unsigned inc = wave_prefix_incl(mycnt);
    if (lane == 63) wofs[wid] = inc;
    __syncthreads();                                   // B4
    unsigned wbase = 0;
    #pragma unroll
    for (int i = 0; i < 8; ++i) wbase += (i < wid) ? wofs[i] : 0u;
    unsigned slot = wbase + inc - mycnt;
    const size_t cbase = (size_t)r * NCAND + (size_t)half * NCL;
    #pragma unroll
    for (int k = 0; k < EPT; ++k) {
        if ((hitm >> k) & 1u) {
            cand_f[cbase + slot] = fv[k];
            cand_i[cbase + slot] =
                (unsigned)((half << 13) + (tid << 2) + (k & 3) + ((k >> 2) << 11));
            ++slot;
        }
    }
    if ((unsigned)tid >= nc && tid < NCL) {            // pad [nc, 128)
        cand_f[cbase + tid] = -INFINITY;               // -> ex = 0 exactly
        cand_i[cbase + tid] = 0x7fffffffu;
    }
}

// ============ K2: barrier-free redundant-wave dynamics + rank (256 x 256) ============
__global__ __launch_bounds__(256, 4) void dyn_kernel(
    const float* __restrict__ cand_f,
    const unsigned* __restrict__ cand_i,
    float* __restrict__ out)
{
    const int tid  = threadIdx.x;
    const int lane = tid & 63;
    const int wid  = tid >> 6;          // 0..3
    const int r    = blockIdx.x;
    const int t_ = r >> 7;
    const int be = r & 127;
    const int b  = be >> 1;
    const int e  = be & 1;

    // private per-wave quadrants: same-wave LDS RAW needs only lgkmcnt,
    // which the compiler inserts -> NO __syncthreads anywhere in K2.
    __shared__ __align__(16) float    khp[4][NCAND];   // 4 KB
    __shared__ __align__(16) unsigned ixp[4][NCAND];   // 4 KB

    float* orow = out + (size_t)(t_ * 64 + b) * (M_ELEMS * 2) + e;

    // each wave loads the FULL candidate set (4 per lane; L1/L2 shared)
    float cf[CPL], cex[CPL], ckh[CPL];
    unsigned ci[CPL];
    #pragma unroll
    for (int k = 0; k < CPL; ++k) {
        cf[k] = cand_f[(size_t)r * NCAND + lane + (k << 6)];
        ci[k] = cand_i[(size_t)r * NCAND + lane + (k << 6)];
    }

    // identical redundant dynamics on every wave (deterministic)
    float cmax = fmaxf(fmaxf(cf[0], cf[1]), fmaxf(cf[2], cf[3]));
    cmax = wave_fmax_bcast(cmax);                      // row max (always cand)
    const float nbw = fmaf(-cmax, C10, 100.0f);        // top ex = 2^100
    #pragma unroll
    for (int k = 0; k < CPL; ++k) {
        cex[k] = __builtin_amdgcn_exp2f(fmaf(cf[k], C10, nbw));
        ckh[k] = 0.0f;
    }
    for (int it = 0; it < KSEL; ++it) {
        float gsum = wave_sum_bcast((cex[0] + cex[1]) + (cex[2] + cex[3]));
        // exponent-range rebase: 90 bits of headroom -> ~1x per row
        const int eb = (int)((__float_as_uint(gsum) >> 23) & 0xFF);
        if (eb < 127 + 10) {                           // gsum < 2^10
            int sh = 354 - eb;                         // rescale gsum -> ~2^100
            if (sh > 254) sh = 254;
            const float s = __uint_as_float((unsigned)sh << 23);
            #pragma unroll
            for (int k = 0; k < CPL; ++k) cex[k] *= s;
            gsum = wave_sum_bcast((cex[0] + cex[1]) + (cex[2] + cex[3]));
            if (!(gsum > 0.0f)) gsum = INFINITY;
        }
        const float rsum = __builtin_amdgcn_rcpf(gsum);
        #pragma unroll
        for (int k = 0; k < CPL; ++k) {
            ckh[k] = fmaf(cex[k], rsum, ckh[k]);              // kh += oh
            const float t  = fmaf(-cex[k], rsum, 1.0f);       // 1 - oh
            const float t2 = t * t;
            const float t4 = t2 * t2;
            const float t8 = t4 * t4;
            cex[k] = cex[k] * t8 * t2;                        // ex *= t^10
        }
    }

    // stash full kh/idx in this wave's private quadrant
    #pragma unroll
    for (int k = 0; k < CPL; ++k) {
        khp[wid][lane + (k << 6)] = ckh[k];
        ixp[wid][lane + (k << 6)] = ci[k];
    }

    // rank candidate (64*wid + lane): myv/myi already in registers
    const float    myv = ckh[wid];
    const unsigned myi = ci[wid];
    unsigned rank = 0;
    #pragma unroll 8
    for (int j = 0; j < NCAND; j += 4) {
        const float4 v  = *reinterpret_cast<const float4*>(&khp[wid][j]);
        const uint4  ii = *reinterpret_cast<const uint4*>(&ixp[wid][j]);
        rank += (v.x > myv || (v.x == myv && ii.x < myi)) ? 1u : 0u;
        rank += (v.y > myv || (v.y == myv && ii.y < myi)) ? 1u : 0u;
        rank += (v.z > myv || (v.z == myv && ii.z < myi)) ? 1u : 0u;
        rank += (v.w > myv || (v.w == myv && ii.w < myi)) ? 1u : 0u;
    }
    if (rank < KSEL && myi < M_ELEMS)
        orow[(size_t)myi * 2] = 1.0f;
}

extern "C" void kernel_launch(void* const* d_in, const int* in_sizes, int n_in,
                              void* d_out, int out_size, void* d_ws, size_t ws_size,
                              hipStream_t stream) {
    const float* scores = (const float*)d_in[0];
    const float* gumbel = (const float*)d_in[1];
    float* out = (float*)d_out;
    const int rows = in_sizes[1] / M_ELEMS;   // 256
    float*    cand_f = (float*)d_ws;
    unsigned* cand_i = (unsigned*)d_ws + (size_t)rows * NCAND;
    screen_kernel<<<rows * 2, 512, 0, stream>>>(scores, gumbel, cand_f, cand_i, out);
    dyn_kernel<<<rows, 256, 0, stream>>>(cand_f, cand_i, out);
}

// Round 15
// 33.283 us; speedup vs baseline: 1.1167x; 1.1149x over previous
//
#include <hip/hip_runtime.h>
#include <math.h>

// GumbelSampler: iterative gumbel-softmax k-hot (k=64) over 256 rows of 16384,
// then straight-through hard top-64. One block per row (grid 256 = 1 block/CU).
//
// FINAL (= round-9 kernel, the measured optimum at 33.3 us / absmax 0.0):
//  - f0-bit histogram (monotone sign-flip transform) -> top-256 candidate cut
//  - conflict-free rotated cutoff scan + DPP prefix scans (no ds_bpermute)
//  - prefix-ordered compaction; wave0 runs 64-iter ex-space dynamics
//    (ex *= (1-oh)^10, po2 exponent rebase) while waves 1-15 zero the output
//  - exact parallel rank (lax.top_k tie semantics) writes the 64 ones
// Structural alternatives (2-kernel split, co-resident half-row screens,
// e-pair blocks, barrier-free redundant-wave dynamics) all measured 34-37 us:
// the ~20 us above model arithmetic is a fixed launch/replay floor, and the
// fused single dispatch minimizes what sits on top of it.

#define BLOCK   1024
#define NWAVES  16
#define M_ELEMS 16384
#define EPT     16                  // elements per thread in block phases
#define KSEL    64
#define NCAND   256                 // candidate capacity
#define CPL     4                   // candidates per lane in wave0
#define NBINS   4096                // transformed f0 bits >> 20
#define THRESH  (M_ELEMS - NCAND)   // 16128: cut where CntLT >= THRESH
#define C10     14.42695019f        // log2(e)/tau

// ---- DPP wave64 helpers ----
template <int CTRL, int RM = 0xF>
__device__ __forceinline__ float dpp_f(float x, float identity) {
    return __int_as_float(__builtin_amdgcn_update_dpp(
        __float_as_int(identity), __float_as_int(x), CTRL, RM, 0xF, false));
}
template <int CTRL, int RM = 0xF>
__device__ __forceinline__ unsigned dpp_u(unsigned x, unsigned identity) {
    return (unsigned)__builtin_amdgcn_update_dpp(
        (int)identity, (int)x, CTRL, RM, 0xF, false);
}
__device__ __forceinline__ float wave_sum_bcast(float x) {
    x += dpp_f<0x111>(x, 0.0f);
    x += dpp_f<0x112>(x, 0.0f);
    x += dpp_f<0x114>(x, 0.0f);
    x += dpp_f<0x118>(x, 0.0f);
    x += dpp_f<0x142>(x, 0.0f);
    x += dpp_f<0x143>(x, 0.0f);
    return __int_as_float(__builtin_amdgcn_readlane(__float_as_int(x), 63));
}
__device__ __forceinline__ float wave_fmax_bcast(float x) {
    x = fmaxf(x, dpp_f<0x111>(x, -INFINITY));
    x = fmaxf(x, dpp_f<0x112>(x, -INFINITY));
    x = fmaxf(x, dpp_f<0x114>(x, -INFINITY));
    x = fmaxf(x, dpp_f<0x118>(x, -INFINITY));
    x = fmaxf(x, dpp_f<0x142>(x, -INFINITY));
    x = fmaxf(x, dpp_f<0x143>(x, -INFINITY));
    return __int_as_float(__builtin_amdgcn_readlane(__float_as_int(x), 63));
}
__device__ __forceinline__ unsigned wave_prefix_incl(unsigned x) {
    x += dpp_u<0x111>(x, 0u);
    x += dpp_u<0x112>(x, 0u);
    x += dpp_u<0x114>(x, 0u);
    x += dpp_u<0x118>(x, 0u);
    x += dpp_u<0x142, 0xA>(x, 0u);     // row_bcast:15 -> rows 1,3
    x += dpp_u<0x143, 0xC>(x, 0u);     // row_bcast:31 -> rows 2,3
    return x;
}

__global__ __launch_bounds__(BLOCK, 4) void gumbel_topk_kernel(
    const float* __restrict__ scores,
    const float* __restrict__ gumbel,
    float* __restrict__ out)
{
    const int tid  = threadIdx.x;
    const int lane = tid & 63;
    const int wid  = tid >> 6;
    // e=0/1 blocks of the same (t,b) write interleaved halves of the same
    // cachelines; put them 128 apart in blockIdx -> same XCD (round-robin %8).
    const int bid = blockIdx.x;
    const int r   = (gridDim.x == 256) ? (((bid & 127) << 1) | (bid >> 7)) : bid;
    const int t_ = r >> 7;
    const int be = r & 127;
    const int b  = be >> 1;
    const int e  = be & 1;

    __shared__ unsigned int          hist[NBINS];        // 16 KB
    __shared__ __align__(16) float    exbuf[NCAND];      // f0 -> kh
    __shared__ __align__(16) unsigned idxbuf[NCAND];
    __shared__ unsigned int          wofs[NWAVES];
    __shared__ unsigned int          cutbin;
    __shared__ unsigned int          candcnt;

    float* orow = out + (size_t)(t_ * 64 + b) * (M_ELEMS * 2) + e;

    // ---- P0: vectorized load; element k=g*4+j -> m = tid*4 + j + g*4096 ----
    float fv[EPT];
    {
        const float* gum = gumbel + (size_t)r * M_ELEMS;
        const float* scb = scores + (size_t)b * (M_ELEMS * 2);   // aligned base
        #pragma unroll
        for (int g = 0; g < 4; ++g) {
            const int mb = (tid << 2) + (g << 12);
            const float4 gv = *reinterpret_cast<const float4*>(&gum[mb]);
            const float4 sa = *reinterpret_cast<const float4*>(&scb[(size_t)mb * 2]);
            const float4 sb = *reinterpret_cast<const float4*>(&scb[(size_t)mb * 2 + 4]);
            float s0, s1, s2, s3;
            if (e == 0) { s0 = sa.x; s1 = sa.z; s2 = sb.x; s3 = sb.z; }
            else        { s0 = sa.y; s1 = sa.w; s2 = sb.y; s3 = sb.w; }
            fv[g * 4 + 0] = s0 + gv.x;
            fv[g * 4 + 1] = s1 + gv.y;
            fv[g * 4 + 2] = s2 + gv.z;
            fv[g * 4 + 3] = s3 + gv.w;
        }
    }
    #pragma unroll
    for (int k = 0; k < NBINS / BLOCK; ++k) hist[tid + k * BLOCK] = 0u;
    __syncthreads();                                   // B1: hist zeroed

    // ---- P1a: histogram of monotone-transformed f0 bits ----
    #pragma unroll
    for (int k = 0; k < EPT; ++k) {
        const unsigned u  = __float_as_uint(fv[k]);
        const unsigned tk = u ^ (unsigned)(((int)u >> 31) | 0x80000000);
        atomicAdd(&hist[tk >> 20], 1u);
    }
    __syncthreads();                                   // B2: hist complete

    // ---- P1b: wave0 cutoff: min bin B with CntLT(B) >= 16128 ----
    if (wid == 0) {
        unsigned part = 0;
        #pragma unroll 8
        for (int j = 0; j < 64; ++j)                   // rotated: bank-spread
            part += hist[(lane << 6) + ((j + lane) & 63)];
        const unsigned P = wave_prefix_incl(part);     // CntLT(64*(lane+1))
        const unsigned long long mk = __ballot(P >= THRESH);  // lane63 always
        const int L = __builtin_ctzll(mk);             // crossing chunk
        const unsigned base = (L > 0)
            ? (unsigned)__builtin_amdgcn_readlane((int)P, L - 1) : 0u;
        const unsigned h2 = hist[(L << 6) + lane];     // consecutive: no conflict
        const unsigned p2 = wave_prefix_incl(h2) + base; // CntLT(L*64+lane+1)
        const unsigned long long mk2 = __ballot(p2 >= THRESH);
        const int j2 = __builtin_ctzll(mk2);           // crossing bin in chunk
        if (lane == 0) {
            cutbin  = (unsigned)((L << 6) + j2 + 1);
            candcnt = M_ELEMS - (unsigned)__builtin_amdgcn_readlane((int)p2, j2);
        }
    }
    __syncthreads();                                   // B3: cut ready
    const unsigned cutKey = cutbin << 20;
    const unsigned nc     = candcnt;

    // ---- P1c: deterministic prefix-ordered compaction (stores f0) ----
    unsigned mycnt = 0, hitm = 0;
    #pragma unroll
    for (int k = 0; k < EPT; ++k) {
        const unsigned u  = __float_as_uint(fv[k]);
        const unsigned tk = u ^ (unsigned)(((int)u >> 31) | 0x80000000);
        const bool c = tk >= cutKey;
        hitm |= (c ? 1u : 0u) << k;
        mycnt += c ? 1u : 0u;
    }
    const unsigned inc = wave_prefix_incl(mycnt);      // DPP, no bpermute
    if (lane == 63) wofs[wid] = inc;
    __syncthreads();                                   // B4: wofs ready
    unsigned wbase = 0;
    #pragma unroll
    for (int i = 0; i < NWAVES; ++i) wbase += (i < wid) ? wofs[i] : 0u;
    unsigned slot = wbase + inc - mycnt;
    #pragma unroll
    for (int k = 0; k < EPT; ++k) {
        if ((hitm >> k) & 1u) {
            exbuf[slot]  = fv[k];
            idxbuf[slot] = (unsigned)((tid << 2) + (k & 3) + ((k >> 2) << 12));
            ++slot;
        }
    }
    if ((unsigned)tid >= nc && tid < NCAND) {          // pad slots [nc, 256)
        exbuf[tid]  = -INFINITY;                       // -> ex = 0 exactly
        idxbuf[tid] = 0x7fffffffu;
    }
    __syncthreads();                                   // B5: candidates ready

    // ---- P2: wave0 dynamics (DPP-only)  ||  waves 1-15 zero the output ----
    if (wid == 0) {
        float cf[CPL], cex[CPL], ckh[CPL];
        #pragma unroll
        for (int k = 0; k < CPL; ++k) cf[k] = exbuf[lane + (k << 6)];
        float cmax = fmaxf(fmaxf(cf[0], cf[1]), fmaxf(cf[2], cf[3]));
        cmax = wave_fmax_bcast(cmax);                  // == row max (always cand)
        const float nbw = fmaf(-cmax, C10, 60.0f);
        #pragma unroll
        for (int k = 0; k < CPL; ++k) {
            cex[k] = __builtin_amdgcn_exp2f(fmaf(cf[k], C10, nbw));
            ckh[k] = 0.0f;
        }
        for (int it = 0; it < KSEL; ++it) {
            float gsum = wave_sum_bcast((cex[0] + cex[1]) + (cex[2] + cex[3]));
            // exponent-range rebase (wave-uniform, rare)
            const int eb = (int)((__float_as_uint(gsum) >> 23) & 0xFF);
            if (eb < 127 + 50) {
                int sh = 314 - eb;
                if (sh > 254) sh = 254;
                const float s = __uint_as_float((unsigned)sh << 23);
                #pragma unroll
                for (int k = 0; k < CPL; ++k) cex[k] *= s;
                gsum = wave_sum_bcast((cex[0] + cex[1]) + (cex[2] + cex[3]));
                if (!(gsum > 0.0f)) gsum = INFINITY;
            }
            const float rsum = __builtin_amdgcn_rcpf(gsum);
            #pragma unroll
            for (int k = 0; k < CPL; ++k) {
                ckh[k] = fmaf(cex[k], rsum, ckh[k]);          // kh += oh
                const float t  = fmaf(-cex[k], rsum, 1.0f);   // 1 - oh
                const float t2 = t * t;
                const float t4 = t2 * t2;
                const float t8 = t4 * t4;
                cex[k] = cex[k] * t8 * t2;                    // ex *= t^10
            }
        }
        #pragma unroll
        for (int k = 0; k < CPL; ++k) exbuf[lane + (k << 6)] = ckh[k]; // kh
    } else {
        // zero-fill this row's output; stores drain at this wave's vmcnt(0)
        // before B6, ordering them behind the 1.0f stores issued after B6.
        for (int m = tid - 64; m < M_ELEMS; m += BLOCK - 64)
            orow[(size_t)m * 2] = 0.0f;
    }
    __syncthreads();                                   // B6: kh + zeros done

    // ---- P3: parallel exact top-64 by rank; winners write 1.0f directly ----
    // rank_i = |{j: kh_j > kh_i or (kh_j == kh_i and idx_j < idx_i)}|
    if (tid < NCAND) {
        const float    myv = exbuf[tid];
        const unsigned myi = idxbuf[tid];
        unsigned rank = 0;
        #pragma unroll 8
        for (int j = 0; j < NCAND; j += 4) {
            const float4 v  = *reinterpret_cast<const float4*>(&exbuf[j]);
            const uint4  ii = *reinterpret_cast<const uint4*>(&idxbuf[j]);
            rank += (v.x > myv || (v.x == myv && ii.x < myi)) ? 1u : 0u;
            rank += (v.y > myv || (v.y == myv && ii.y < myi)) ? 1u : 0u;
            rank += (v.z > myv || (v.z == myv && ii.z < myi)) ? 1u : 0u;
            rank += (v.w > myv || (v.w == myv && ii.w < myi)) ? 1u : 0u;
        }
        if (rank < KSEL && myi < M_ELEMS)
            orow[(size_t)myi * 2] = 1.0f;
    }
}

extern "C" void kernel_launch(void* const* d_in, const int* in_sizes, int n_in,
                              void* d_out, int out_size, void* d_ws, size_t ws_size,
                              hipStream_t stream) {
    const float* scores = (const float*)d_in[0];
    const float* gumbel = (const float*)d_in[1];
    float* out = (float*)d_out;
    const int rows = in_sizes[1] / M_ELEMS;   // 256
    gumbel_topk_kernel<<<rows, BLOCK, 0, stream>>>(scores, gumbel, out);
}